// Round 14
// baseline (450.873 us; speedup 1.0000x reference)
//
#include <hip/hip_runtime.h>

typedef unsigned int u32;
typedef unsigned short ushort_t;

typedef __attribute__((ext_vector_type(8)))  short bf16x8;   // 8 bf16 = 4 VGPR
typedef __attribute__((ext_vector_type(16))) float f32x16;   // 32x32 MFMA acc

#define ENS 10
#define NU 256
#define NHID 7
#define IN_DIM 6
#define OUT_DIM 201
#define BATCH 16384

// ---- 32x32x16 bf16 fragment layouts ----
// A: lane l holds m = l&31,  k = (l>>5)*8 + j   (j=0..7)
// B: lane l holds n = l&31,  k = (l>>5)*8 + j
// C/D: lane l holds col = l&31, row = (r&3) + 8*(r>>2) + 4*(l>>5)  (r=0..15)

// fragment-array sizes in ushort (bf16) elements, per plane
#define WH_PER 65536                  // per (layer,ens): 16 s * 8 ctg * 64 * 8
#define WH_TOT (NHID * ENS * WH_PER)  // 4,587,520
#define W0_PER 4096                   // per ens: 8 ctg * 64 * 8 (K pad 6->16)
#define W0_TOT (ENS * W0_PER)
#define WF_PER 57344                  // per ens: 16 s * 7 ctg * 64 * 8 (N pad 201->224)
#define WF_TOT (ENS * WF_PER)
#define X_TOT ((BATCH / 32) * 64 * 8) // 262,144 (K pad 6->16)

// ws layout (ushort units); weights ~21.9 MB + P partials 13.8 MB
#define O_WHH 0
#define O_WHL (O_WHH + WH_TOT)
#define O_W0H (O_WHL + WH_TOT)
#define O_W0L (O_W0H + W0_TOT)
#define O_WFH (O_W0L + W0_TOT)
#define O_WFL (O_WFH + WF_TOT)
#define O_XH  (O_WFL + WF_TOT)
#define O_XL  (O_XH + X_TOT)
#define O_P   (O_XL + X_TOT)          // float P[ENS][BATCH][21] from here

#define NG 21    // jo-groups per ensemble
#define RS 264   // act plane row stride (ushort)
#define YS 204   // y-staging row stride (float)
#define RT 64    // batch rows per WG

__device__ __forceinline__ u32 bf16_rne(float f) {
    u32 u = __float_as_uint(f);
    return (u + 0x7FFFu + ((u >> 16) & 1u)) >> 16;
}
__device__ __forceinline__ void split2(float f, u32& h, u32& l) {
    h = bf16_rne(f);
    float fh = __uint_as_float(h << 16);
    l = bf16_rne(f - fh);
}

// HW packed f32->bf16 conversion (no builtin on gfx950 -> inline asm)
__device__ __forceinline__ u32 cvt_pk_bf16(float s0, float s1) {
    u32 r;
    asm("v_cvt_pk_bf16_f32 %0, %1, %2" : "=v"(r) : "v"(s0), "v"(s1));
    return r;
}

// asm-issued B loads (pinned issue point; counted by manual vmcnt)
#define GLOAD(dst, p) \
    asm volatile("global_load_dwordx4 %0, %1, off" : "=v"(dst) : "v"(p))
#define VMWAIT12 asm volatile("s_waitcnt vmcnt(12)" ::: "memory")
#define VMWAIT8  asm volatile("s_waitcnt vmcnt(8)"  ::: "memory")
#define VMWAIT4  asm volatile("s_waitcnt vmcnt(4)"  ::: "memory")
#define VMWAIT0  asm volatile("s_waitcnt vmcnt(0)"  ::: "memory")
// raw barrier: LDS-fence only — does NOT drain vmcnt (B loads stay in flight)
#define LBAR() do { asm volatile("s_waitcnt lgkmcnt(0)" ::: "memory"); \
                    __builtin_amdgcn_s_barrier(); } while (0)

// ---------------- prep kernels: fp32 -> hi/lo bf16, B/A-frag-linear ----------------

__global__ __launch_bounds__(256) void prep_wh(const float* __restrict__ Wh,
                                               ushort_t* __restrict__ dH, ushort_t* __restrict__ dL) {
    int i = blockIdx.x * 256 + threadIdx.x;
    if (i >= WH_TOT) return;
    int j = i & 7, l = (i >> 3) & 63, ctg = (i >> 9) & 7, s = (i >> 12) & 15, le = i >> 16;
    int k = s * 16 + ((l >> 5) << 3) + j;
    int n = ctg * 32 + (l & 31);
    float v = Wh[(size_t)le * 65536 + k * 256 + n];
    u32 h, lo; split2(v, h, lo);
    dH[i] = (ushort_t)h; dL[i] = (ushort_t)lo;
}

__global__ __launch_bounds__(256) void prep_w0(const float* __restrict__ W0,
                                               ushort_t* __restrict__ dH, ushort_t* __restrict__ dL) {
    int i = blockIdx.x * 256 + threadIdx.x;
    if (i >= W0_TOT) return;
    int j = i & 7, l = (i >> 3) & 63, ctg = (i >> 9) & 7, e = i >> 12;
    int k = ((l >> 5) << 3) + j;       // 0..15, valid < 6
    int n = ctg * 32 + (l & 31);
    float v = (k < IN_DIM) ? W0[(e * IN_DIM + k) * 256 + n] : 0.0f;
    u32 h, lo; split2(v, h, lo);
    dH[i] = (ushort_t)h; dL[i] = (ushort_t)lo;
}

__global__ __launch_bounds__(256) void prep_wf(const float* __restrict__ Wf,
                                               ushort_t* __restrict__ dH, ushort_t* __restrict__ dL) {
    int i = blockIdx.x * 256 + threadIdx.x;
    if (i >= WF_TOT) return;
    int e = i / WF_PER;
    int idx = i - e * WF_PER;
    int j = idx & 7, l = (idx >> 3) & 63, g = idx >> 9;  // g = s*7+ct, 0..111
    int s = g / 7, ct = g - s * 7;
    int k = s * 16 + ((l >> 5) << 3) + j;
    int n = ct * 32 + (l & 31);
    float v = (n < OUT_DIM) ? Wf[((size_t)e * 256 + k) * OUT_DIM + n] : 0.0f;
    u32 h, lo; split2(v, h, lo);
    dH[i] = (ushort_t)h; dL[i] = (ushort_t)lo;
}

__global__ __launch_bounds__(256) void prep_x(const float* __restrict__ x,
                                              ushort_t* __restrict__ dH, ushort_t* __restrict__ dL) {
    int i = blockIdx.x * 256 + threadIdx.x;
    if (i >= X_TOT) return;
    int j = i & 7, l = (i >> 3) & 63, rt = i >> 9;   // rt = 0..511
    int row = rt * 32 + (l & 31);
    int k = ((l >> 5) << 3) + j;
    float v = (k < IN_DIM) ? x[row * IN_DIM + k] : 0.0f;
    u32 h, lo; split2(v, h, lo);
    dH[i] = (ushort_t)h; dL[i] = (ushort_t)lo;
}

// out[b][jo] = 0.1 * (P[e1][b][jo-base(e1)] + (e2!=e1 ? P[e2][b][jo-base(e2)] : 0))
__global__ __launch_bounds__(256) void reduce_mean(const float* __restrict__ P,
                                                   float* __restrict__ out) {
    int i = blockIdx.x * 256 + threadIdx.x;
    if (i >= BATCH * OUT_DIM) return;
    int b = i / OUT_DIM, jo = i - b * OUT_DIM;
    int f0 = jo * 10;
    int e1 = f0 / OUT_DIM;
    int e2 = (f0 + 9) / OUT_DIM;
    int g1 = jo - (e1 * OUT_DIM) / 10;
    float s = P[((size_t)e1 * BATCH + b) * NG + g1];
    if (e2 != e1) {
        int g2 = jo - (e2 * OUT_DIM) / 10;
        s += P[((size_t)e2 * BATCH + b) * NG + g2];
    }
    out[i] = 0.1f * s;
}

#define MFMA32(A, B, C) __builtin_amdgcn_mfma_f32_32x32x16_bf16((A), (B), (C), 0, 0, 0)

// Epilogue: bias+relu, hi/lo split via HW v_cvt_pk_bf16_f32 (R11 champion form).
__device__ __forceinline__ void store_act(ushort_t* actH, ushort_t* actL,
    const f32x16 (&acc)[2][2], float bv0, float bv1, int colA, int colB, int rowb)
{
#pragma unroll
    for (int mt = 0; mt < 2; ++mt)
#pragma unroll
        for (int c = 0; c < 2; ++c) {
            const float bv = c ? bv1 : bv0;
            const int col = c ? colB : colA;
#pragma unroll
            for (int q = 0; q < 4; ++q) {
#pragma unroll
                for (int p = 0; p < 2; ++p) {
                    int r0 = q * 4 + p * 2;
                    int row = mt * 32 + rowb + 8 * q + p * 2;
                    float g0 = fmaxf(acc[mt][c][r0] + bv, 0.0f);
                    float g1 = fmaxf(acc[mt][c][r0 + 1] + bv, 0.0f);
                    u32 hp = cvt_pk_bf16(g0, g1);
                    float fh0 = __uint_as_float(hp << 16);
                    float fh1 = __uint_as_float(hp & 0xFFFF0000u);
                    u32 lp = cvt_pk_bf16(g0 - fh0, g1 - fh1);
                    actH[row * RS + col]       = (ushort_t)hp;
                    actH[(row + 1) * RS + col] = (ushort_t)(hp >> 16);
                    actL[row * RS + col]       = (ushort_t)lp;
                    actL[(row + 1) * RS + col] = (ushort_t)(lp >> 16);
                }
            }
        }
}

// ---------------- fused MLP: 32x32x16 split-bf16, 64x64 wave tiles ----------------
// grid 2560 (XCD-swizzled); 256 threads = 4 waves (mt=2, ct=2, 12 MFMAs/k-step).
// LDS 75.6 KB -> 2 WG/CU. B-operand: 4-slot asm register pipeline with 3-step
// cover: prologue issues chunks 0,1,2; each step issues s+3 then vmcnt(12)
// (retires exactly chunk s). Never drained mid-stream; lgkm-only barriers.
__global__ __launch_bounds__(256, 2)
void mlp_mfma(const ushort_t* __restrict__ wsU,
              const float* __restrict__ b0g, const float* __restrict__ bhg,
              const float* __restrict__ bfg, float* __restrict__ Pws) {
    __shared__ __align__(16) ushort_t smem[2 * RT * RS];  // 67,584 B, aliased:
    ushort_t* actH = smem;                                //   [64][RS] hi plane
    ushort_t* actL = smem + RT * RS;                      //   [64][RS] lo plane
    float*    yst  = (float*)smem;                        //   [64][YS] final-y staging
    __shared__ float biasLds[NHID * NU + 224];            // 8,064 B: bh[7][256], bf[224]

    const int tid  = threadIdx.x;
    const int lane = tid & 63;
    const int cg   = tid >> 6;        // wave 0..3
    const int l31  = lane & 31;
    const int lh   = lane >> 5;       // 0..1
    const int ctg0 = cg * 2;

    // XCD-aware bijective swizzle: 2560 WGs, 8 XCDs, 320/XCD
    const int bid  = blockIdx.x;
    const int work = (bid & 7) * 320 + (bid >> 3);
    const int e    = work >> 8;       // ensemble 0..9
    const int rb   = work & 255;      // 64-row block 0..255
    const int rowWG = rb * RT;

    const size_t lo8 = (size_t)lane * 8;
    const ushort_t* arH0 = actH + l31 * RS;
    const ushort_t* arL0 = actL + l31 * RS;
    const ushort_t* arH1 = actH + (32 + l31) * RS;
    const ushort_t* arL1 = actL + (32 + l31) * RS;
    const int rowb = lh * 4;          // epilogue row base within 32-tile
    const int colA = ctg0 * 32 + l31, colB = colA + 32;

    // final-layer clamped ct indices (ctg>6 duplicates 6; masked at epilogue)
    const int c0f = (ctg0 > 6) ? 6 : ctg0;
    const int c1f = (ctg0 + 1 > 6) ? 6 : ctg0 + 1;

    f32x16 acc[2][2];
    bf16x8 aH[2], aL[2];
    bf16x8 sB0h[4], sB0l[4], sB1h[4], sB1l[4];   // 4-slot B pipeline (slot = chunk&3)

    // ---- stage hidden+final biases into LDS (vm loads drained by VMWAIT0 below) ----
#pragma unroll
    for (int it = 0; it < NHID; ++it) {
        int i = it * 256 + tid;
        int L = i >> 8, c = i & 255;
        biasLds[i] = bhg[(size_t)(L * ENS + e) * NU + c];
    }
    if (tid < 224)
        biasLds[NHID * NU + tid] = (tid < OUT_DIM) ? bfg[e * OUT_DIM + tid] : 0.0f;

    // ================ layer 0 (K padded 6->16, single k-step) ================
    {
        const ushort_t* B0H = wsU + O_W0H + (size_t)e * W0_PER;
        const ushort_t* B0L = wsU + O_W0L + (size_t)e * W0_PER;
        bf16x8 b0h0 = *(const bf16x8*)(B0H + (size_t)ctg0 * 512 + lo8);
        bf16x8 b0l0 = *(const bf16x8*)(B0L + (size_t)ctg0 * 512 + lo8);
        bf16x8 b0h1 = *(const bf16x8*)(B0H + (size_t)(ctg0 + 1) * 512 + lo8);
        bf16x8 b0l1 = *(const bf16x8*)(B0L + (size_t)(ctg0 + 1) * 512 + lo8);
        bf16x8 xh[2], xl[2];
#pragma unroll
        for (int mt = 0; mt < 2; ++mt) {
            size_t xoff = ((size_t)(rb * 2 + mt) * 64 + lane) * 8;
            xh[mt] = *(const bf16x8*)(wsU + O_XH + xoff);
            xl[mt] = *(const bf16x8*)(wsU + O_XL + xoff);
        }
        float bv0 = b0g[e * NU + colA];
        float bv1 = b0g[e * NU + colB];

        f32x16 z = 0.0f;
#pragma unroll
        for (int mt = 0; mt < 2; ++mt) {
            f32x16 a0 = z, a1 = z;
            a0 = MFMA32(xh[mt], b0h0, a0);
            a1 = MFMA32(xh[mt], b0h1, a1);
            a0 = MFMA32(xl[mt], b0h0, a0);
            a1 = MFMA32(xl[mt], b0h1, a1);
            a0 = MFMA32(xh[mt], b0l0, a0);
            a1 = MFMA32(xh[mt], b0l1, a1);
            acc[mt][0] = a0; acc[mt][1] = a1;
        }

        // drain ALL compiler vm loads (x, W0, b0, bias staging), then asm-issue
        // hidden-L0 chunks 0,1,2 — from here on, vmcnt counts ONLY our GLOADs.
        VMWAIT0;
        {
            const ushort_t* BH0 = wsU + O_WHH + (size_t)e * WH_PER;
            const ushort_t* BL0 = wsU + O_WHL + (size_t)e * WH_PER;
#pragma unroll
            for (int cc = 0; cc < 3; ++cc) {
                size_t off = ((size_t)(cc * 8 + ctg0)) * 512 + lo8;
                GLOAD(sB0h[cc], BH0 + off);
                GLOAD(sB0l[cc], BL0 + off);
                GLOAD(sB1h[cc], BH0 + off + 512);
                GLOAD(sB1l[cc], BL0 + off + 512);
            }
        }
        store_act(actH, actL, acc, bv0, bv1, colA, colB, rowb);
        LBAR();   // lgkm-only: act + bias table visible; B loads stay in flight
    }

    // ================ 7 hidden layers (K=256, 16 k-steps, counted B stream) ================
    const ushort_t* BH = wsU + O_WHH + (size_t)e * WH_PER;
    const ushort_t* BL = wsU + O_WHL + (size_t)e * WH_PER;
#pragma unroll 1
    for (int L = 0; L < NHID; ++L) {
        // bias via LDS (lgkm, not vm — keeps the vmcnt stream exact)
        float bv0 = biasLds[L * NU + colA];
        float bv1 = biasLds[L * NU + colB];

        // next-layer chunk-0/1/2 addresses (runtime values, compile-time indices)
        const ushort_t *nA0[3], *nB0[3], *nA1[3], *nB1[3];
        if (L < NHID - 1) {
            const ushort_t* a_ = BH + (size_t)ENS * WH_PER;
            const ushort_t* b_ = BL + (size_t)ENS * WH_PER;
#pragma unroll
            for (int cc = 0; cc < 3; ++cc) {
                size_t off = ((size_t)(cc * 8 + ctg0)) * 512 + lo8;
                nA0[cc] = a_ + off;       nB0[cc] = b_ + off;
                nA1[cc] = a_ + off + 512; nB1[cc] = b_ + off + 512;
            }
        } else {
            const ushort_t* fh = wsU + O_WFH + (size_t)e * WF_PER;
            const ushort_t* fl = wsU + O_WFL + (size_t)e * WF_PER;
#pragma unroll
            for (int cc = 0; cc < 3; ++cc) {
                size_t o0_ = ((size_t)(cc * 7 + c0f)) * 512 + lo8;
                size_t o1_ = ((size_t)(cc * 7 + c1f)) * 512 + lo8;
                nA0[cc] = fh + o0_; nB0[cc] = fl + o0_;
                nA1[cc] = fh + o1_; nB1[cc] = fl + o1_;
            }
        }

        f32x16 z = 0.0f;
#pragma unroll
        for (int mt = 0; mt < 2; ++mt) { acc[mt][0] = z; acc[mt][1] = z; }
        aH[0] = *(const bf16x8*)(arH0 + lh * 8);
        aL[0] = *(const bf16x8*)(arL0 + lh * 8);
        aH[1] = *(const bf16x8*)(arH1 + lh * 8);
        aL[1] = *(const bf16x8*)(arL1 + lh * 8);

#pragma unroll
        for (int s = 0; s < 16; ++s) {
            // A prefetch (s+1), compiler-scheduled
            bf16x8 aHn[2], aLn[2];
            if (s < 15) {
                int kn = (s + 1) * 16 + lh * 8;
                aHn[0] = *(const bf16x8*)(arH0 + kn);
                aLn[0] = *(const bf16x8*)(arL0 + kn);
                aHn[1] = *(const bf16x8*)(arH1 + kn);
                aLn[1] = *(const bf16x8*)(arL1 + kn);
            }
            // B issue: chunk s+3 into slot (s+3)&3 (chunks >=16 are next layer's 0/1/2)
            {
                const ushort_t *pA0, *pB0, *pA1, *pB1;
                if (s < 13) {
                    size_t off = ((size_t)((s + 3) * 8 + ctg0)) * 512 + lo8;
                    pA0 = BH + off; pB0 = BL + off;
                    pA1 = BH + off + 512; pB1 = BL + off + 512;
                } else {
                    pA0 = nA0[s - 13]; pB0 = nB0[s - 13];
                    pA1 = nA1[s - 13]; pB1 = nB1[s - 13];
                }
                GLOAD(sB0h[(s + 3) & 3], pA0);
                GLOAD(sB0l[(s + 3) & 3], pB0);
                GLOAD(sB1h[(s + 3) & 3], pA1);
                GLOAD(sB1l[(s + 3) & 3], pB1);
            }
            VMWAIT12;                                  // retires exactly chunk s
            __builtin_amdgcn_sched_barrier(0);         // rule 18: fence the wait
#pragma unroll
            for (int mt = 0; mt < 2; ++mt) {
                f32x16 a0 = acc[mt][0], a1 = acc[mt][1];
                a0 = MFMA32(aH[mt], sB0h[s & 3], a0);
                a1 = MFMA32(aH[mt], sB1h[s & 3], a1);
                a0 = MFMA32(aL[mt], sB0h[s & 3], a0);
                a1 = MFMA32(aL[mt], sB1h[s & 3], a1);
                a0 = MFMA32(aH[mt], sB0l[s & 3], a0);
                a1 = MFMA32(aH[mt], sB1l[s & 3], a1);
                acc[mt][0] = a0; acc[mt][1] = a1;
            }
            if (s < 15) {
                aH[0] = aHn[0]; aL[0] = aLn[0];
                aH[1] = aHn[1]; aL[1] = aLn[1];
            }
        }

        LBAR();   // all act reads of this layer done (lgkm); B loads keep flying
        store_act(actH, actL, acc, bv0, bv1, colA, colB, rowb);
        LBAR();   // act writes visible
        BH += (size_t)ENS * WH_PER;
        BL += (size_t)ENS * WH_PER;
    }

    // ================ final layer (N padded 201->224 = 7 ct-tiles) ================
    {
        const ushort_t* FH = wsU + O_WFH + (size_t)e * WF_PER;
        const ushort_t* FL = wsU + O_WFL + (size_t)e * WF_PER;
        int o0 = ctg0 * 32 + l31;
        int o1 = (ctg0 + 1) * 32 + l31;
        bool v0 = (o0 < OUT_DIM);
        bool v1 = (ctg0 + 1 < 7) && (o1 < OUT_DIM);
        float bf0 = v0 ? biasLds[NHID * NU + o0] : 0.0f;   // LDS reads (lgkm)
        float bf1 = v1 ? biasLds[NHID * NU + o1] : 0.0f;

        f32x16 z = 0.0f;
#pragma unroll
        for (int mt = 0; mt < 2; ++mt) { acc[mt][0] = z; acc[mt][1] = z; }
        aH[0] = *(const bf16x8*)(arH0 + lh * 8);
        aL[0] = *(const bf16x8*)(arL0 + lh * 8);
        aH[1] = *(const bf16x8*)(arH1 + lh * 8);
        aL[1] = *(const bf16x8*)(arL1 + lh * 8);

#pragma unroll
        for (int s = 0; s < 16; ++s) {
            bf16x8 aHn[2], aLn[2];
            if (s < 15) {
                int kn = (s + 1) * 16 + lh * 8;
                aHn[0] = *(const bf16x8*)(arH0 + kn);
                aLn[0] = *(const bf16x8*)(arL0 + kn);
                aHn[1] = *(const bf16x8*)(arH1 + kn);
                aLn[1] = *(const bf16x8*)(arL1 + kn);
            }
            if (s < 13) {
                size_t o0_ = ((size_t)((s + 3) * 7 + c0f)) * 512 + lo8;
                size_t o1_ = ((size_t)((s + 3) * 7 + c1f)) * 512 + lo8;
                GLOAD(sB0h[(s + 3) & 3], FH + o0_);
                GLOAD(sB0l[(s + 3) & 3], FL + o0_);
                GLOAD(sB1h[(s + 3) & 3], FH + o1_);
                GLOAD(sB1l[(s + 3) & 3], FL + o1_);
            }
            if (s < 13)      { VMWAIT12; }
            else if (s == 13){ VMWAIT8;  }
            else if (s == 14){ VMWAIT4;  }
            else             { VMWAIT0;  }
            __builtin_amdgcn_sched_barrier(0);
#pragma unroll
            for (int mt = 0; mt < 2; ++mt) {
                f32x16 a0 = acc[mt][0], a1 = acc[mt][1];
                a0 = MFMA32(aH[mt], sB0h[s & 3], a0);
                a1 = MFMA32(aH[mt], sB1h[s & 3], a1);
                a0 = MFMA32(aL[mt], sB0h[s & 3], a0);
                a1 = MFMA32(aL[mt], sB1h[s & 3], a1);
                a0 = MFMA32(aH[mt], sB0l[s & 3], a0);
                a1 = MFMA32(aH[mt], sB1l[s & 3], a1);
                acc[mt][0] = a0; acc[mt][1] = a1;
            }
            if (s < 15) {
                aH[0] = aHn[0]; aL[0] = aLn[0];
                aH[1] = aHn[1]; aL[1] = aLn[1];
            }
        }

        // ---- NO atomics: stage y into LDS, reduce groups-of-10, store partials ----
        LBAR();   // all act reads done; safe to overwrite smem with yst
#pragma unroll
        for (int mt = 0; mt < 2; ++mt)
#pragma unroll
            for (int r = 0; r < 16; ++r) {
                int row = mt * 32 + rowb + (r & 3) + 8 * (r >> 2);
                if (v0) yst[row * YS + o0] = acc[mt][0][r] + bf0;
                if (v1) yst[row * YS + o1] = acc[mt][1][r] + bf1;
            }
        LBAR();

        // partial sums: P[e][rowWG+row][g] = sum over flatc in [jo*10, jo*10+10)
        const int base_jo = (e * OUT_DIM) / 10;
        const int e201 = e * OUT_DIM;
        for (int it = tid; it < RT * NG; it += 256) {
            int row = it / NG;
            int g   = it - row * NG;
            int f0  = (base_jo + g) * 10;
            float sm = 0.0f;
#pragma unroll
            for (int d = 0; d < 10; ++d) {
                int oo = f0 + d - e201;
                if (oo >= 0 && oo < OUT_DIM) sm += yst[row * YS + oo];
            }
            Pws[((size_t)e * BATCH + rowWG + row) * NG + g] = sm;
        }
    }
}

extern "C" void kernel_launch(void* const* d_in, const int* in_sizes, int n_in,
                              void* d_out, int out_size, void* d_ws, size_t ws_size,
                              hipStream_t stream) {
    const float* x  = (const float*)d_in[0];
    const float* W0 = (const float*)d_in[1];
    const float* b0 = (const float*)d_in[2];
    const float* Wh = (const float*)d_in[3];
    const float* bh = (const float*)d_in[4];
    const float* Wf = (const float*)d_in[5];
    const float* bf = (const float*)d_in[6];
    float* out = (float*)d_out;
    ushort_t* ws = (ushort_t*)d_ws;            // needs ~36 MB
    float* Pws = (float*)(ws + O_P);           // P[ENS][BATCH][NG]

    prep_wh<<<(WH_TOT + 255) / 256, 256, 0, stream>>>(Wh, ws + O_WHH, ws + O_WHL);
    prep_w0<<<(W0_TOT + 255) / 256, 256, 0, stream>>>(W0, ws + O_W0H, ws + O_W0L);
    prep_wf<<<(WF_TOT + 255) / 256, 256, 0, stream>>>(Wf, ws + O_WFH, ws + O_WFL);
    prep_x <<<(X_TOT  + 255) / 256, 256, 0, stream>>>(x,  ws + O_XH,  ws + O_XL);

    mlp_mfma<<<dim3(BATCH / RT * ENS), 256, 0, stream>>>(ws, b0, bh, bf, Pws);
    reduce_mean<<<(BATCH * OUT_DIM + 255) / 256, 256, 0, stream>>>(Pws, out);
}

// Round 15
// 422.218 us; speedup vs baseline: 1.0679x; 1.0679x over previous
//
#include <hip/hip_runtime.h>

typedef unsigned int u32;
typedef unsigned short ushort_t;

typedef __attribute__((ext_vector_type(8)))  short bf16x8;   // 8 bf16 = 4 VGPR
typedef __attribute__((ext_vector_type(16))) float f32x16;   // 32x32 MFMA acc

#define ENS 10
#define NU 256
#define NHID 7
#define IN_DIM 6
#define OUT_DIM 201
#define BATCH 16384

// ---- 32x32x16 bf16 fragment layouts ----
// A: lane l holds m = l&31,  k = (l>>5)*8 + j   (j=0..7)
// B: lane l holds n = l&31,  k = (l>>5)*8 + j
// C/D: lane l holds col = l&31, row = (r&3) + 8*(r>>2) + 4*(l>>5)  (r=0..15)

// fragment-array sizes in ushort (bf16) elements, per plane
#define WH_PER 65536                  // per (layer,ens): 16 s * 8 ctg * 64 * 8
#define WH_TOT (NHID * ENS * WH_PER)  // 4,587,520
#define W0_PER 4096                   // per ens: 8 ctg * 64 * 8 (K pad 6->16)
#define W0_TOT (ENS * W0_PER)
#define WF_PER 57344                  // per ens: 16 s * 7 ctg * 64 * 8 (N pad 201->224)
#define WF_TOT (ENS * WF_PER)
#define X_TOT ((BATCH / 32) * 64 * 8) // 262,144 (K pad 6->16)

// ws layout (ushort units); weights ~21.9 MB + P partials 13.8 MB
#define O_WHH 0
#define O_WHL (O_WHH + WH_TOT)
#define O_W0H (O_WHL + WH_TOT)
#define O_W0L (O_W0H + W0_TOT)
#define O_WFH (O_W0L + W0_TOT)
#define O_WFL (O_WFH + WF_TOT)
#define O_XH  (O_WFL + WF_TOT)
#define O_XL  (O_XH + X_TOT)
#define O_P   (O_XL + X_TOT)          // float P[ENS][BATCH][21] from here

#define NG 21    // jo-groups per ensemble
#define RS 264   // act plane row stride (ushort)
#define YS 204   // y-staging row stride (float)
#define RT 64    // batch rows per WG

#define PREP_TOT (WH_TOT + W0_TOT + WF_TOT + X_TOT)

__device__ __forceinline__ u32 bf16_rne(float f) {
    u32 u = __float_as_uint(f);
    return (u + 0x7FFFu + ((u >> 16) & 1u)) >> 16;
}
__device__ __forceinline__ void split2(float f, u32& h, u32& l) {
    h = bf16_rne(f);
    float fh = __uint_as_float(h << 16);
    l = bf16_rne(f - fh);
}

// HW packed f32->bf16 conversion (no builtin on gfx950 -> inline asm)
__device__ __forceinline__ u32 cvt_pk_bf16(float s0, float s1) {
    u32 r;
    asm("v_cvt_pk_bf16_f32 %0, %1, %2" : "=v"(r) : "v"(s0), "v"(s1));
    return r;
}

// asm-issued B loads (pinned issue point; counted by manual vmcnt)
#define GLOAD(dst, p) \
    asm volatile("global_load_dwordx4 %0, %1, off" : "=v"(dst) : "v"(p))
#define VMWAIT4 asm volatile("s_waitcnt vmcnt(4)" ::: "memory")
#define VMWAIT0 asm volatile("s_waitcnt vmcnt(0)" ::: "memory")
// raw barrier: LDS-fence only — does NOT drain vmcnt (B loads stay in flight)
#define LBAR() do { asm volatile("s_waitcnt lgkmcnt(0)" ::: "memory"); \
                    __builtin_amdgcn_s_barrier(); } while (0)

// ---------------- fused prep: fp32 -> hi/lo bf16, B/A-frag-linear layouts ----------------
// One kernel covers Wh, W0, Wf, x (linear index over the concatenated ranges).
__global__ __launch_bounds__(256) void prep_all(const float* __restrict__ Wh,
                                                const float* __restrict__ W0,
                                                const float* __restrict__ Wf,
                                                const float* __restrict__ x,
                                                ushort_t* __restrict__ ws) {
    int i = blockIdx.x * 256 + threadIdx.x;
    if (i >= PREP_TOT) return;
    float v;
    ushort_t *dH, *dL;
    int di;
    if (i < WH_TOT) {
        di = i;
        int j = di & 7, l = (di >> 3) & 63, ctg = (di >> 9) & 7, s = (di >> 12) & 15, le = di >> 16;
        int k = s * 16 + ((l >> 5) << 3) + j;
        int n = ctg * 32 + (l & 31);
        v = Wh[(size_t)le * 65536 + k * 256 + n];
        dH = ws + O_WHH; dL = ws + O_WHL;
    } else if (i < WH_TOT + W0_TOT) {
        di = i - WH_TOT;
        int j = di & 7, l = (di >> 3) & 63, ctg = (di >> 9) & 7, e = di >> 12;
        int k = ((l >> 5) << 3) + j;       // 0..15, valid < 6
        int n = ctg * 32 + (l & 31);
        v = (k < IN_DIM) ? W0[(e * IN_DIM + k) * 256 + n] : 0.0f;
        dH = ws + O_W0H; dL = ws + O_W0L;
    } else if (i < WH_TOT + W0_TOT + WF_TOT) {
        di = i - (WH_TOT + W0_TOT);
        int e = di / WF_PER;
        int idx = di - e * WF_PER;
        int j = idx & 7, l = (idx >> 3) & 63, g = idx >> 9;  // g = s*7+ct, 0..111
        int s = g / 7, ct = g - s * 7;
        int k = s * 16 + ((l >> 5) << 3) + j;
        int n = ct * 32 + (l & 31);
        v = (n < OUT_DIM) ? Wf[((size_t)e * 256 + k) * OUT_DIM + n] : 0.0f;
        dH = ws + O_WFH; dL = ws + O_WFL;
    } else {
        di = i - (WH_TOT + W0_TOT + WF_TOT);
        int j = di & 7, l = (di >> 3) & 63, rt = di >> 9;   // rt = 0..511
        int row = rt * 32 + (l & 31);
        int k = ((l >> 5) << 3) + j;
        v = (k < IN_DIM) ? x[row * IN_DIM + k] : 0.0f;
        dH = ws + O_XH; dL = ws + O_XL;
    }
    u32 h, lo; split2(v, h, lo);
    dH[di] = (ushort_t)h; dL[di] = (ushort_t)lo;
}

// out[b][jo] = 0.1 * (P[e1][b][jo-base(e1)] + (e2!=e1 ? P[e2][b][jo-base(e2)] : 0))
__global__ __launch_bounds__(256) void reduce_mean(const float* __restrict__ P,
                                                   float* __restrict__ out) {
    int i = blockIdx.x * 256 + threadIdx.x;
    if (i >= BATCH * OUT_DIM) return;
    int b = i / OUT_DIM, jo = i - b * OUT_DIM;
    int f0 = jo * 10;
    int e1 = f0 / OUT_DIM;
    int e2 = (f0 + 9) / OUT_DIM;
    int g1 = jo - (e1 * OUT_DIM) / 10;
    float s = P[((size_t)e1 * BATCH + b) * NG + g1];
    if (e2 != e1) {
        int g2 = jo - (e2 * OUT_DIM) / 10;
        s += P[((size_t)e2 * BATCH + b) * NG + g2];
    }
    out[i] = 0.1f * s;
}

#define MFMA32(A, B, C) __builtin_amdgcn_mfma_f32_32x32x16_bf16((A), (B), (C), 0, 0, 0)

// Epilogue: bias+relu, hi/lo split via HW v_cvt_pk_bf16_f32 (R11 champion form).
__device__ __forceinline__ void store_act(ushort_t* actH, ushort_t* actL,
    const f32x16 (&acc)[2][2], float bv0, float bv1, int colA, int colB, int rowb)
{
#pragma unroll
    for (int mt = 0; mt < 2; ++mt)
#pragma unroll
        for (int c = 0; c < 2; ++c) {
            const float bv = c ? bv1 : bv0;
            const int col = c ? colB : colA;
#pragma unroll
            for (int q = 0; q < 4; ++q) {
#pragma unroll
                for (int p = 0; p < 2; ++p) {
                    int r0 = q * 4 + p * 2;
                    int row = mt * 32 + rowb + 8 * q + p * 2;
                    float g0 = fmaxf(acc[mt][c][r0] + bv, 0.0f);
                    float g1 = fmaxf(acc[mt][c][r0 + 1] + bv, 0.0f);
                    u32 hp = cvt_pk_bf16(g0, g1);
                    float fh0 = __uint_as_float(hp << 16);
                    float fh1 = __uint_as_float(hp & 0xFFFF0000u);
                    u32 lp = cvt_pk_bf16(g0 - fh0, g1 - fh1);
                    actH[row * RS + col]       = (ushort_t)hp;
                    actH[(row + 1) * RS + col] = (ushort_t)(hp >> 16);
                    actL[row * RS + col]       = (ushort_t)lp;
                    actL[(row + 1) * RS + col] = (ushort_t)(lp >> 16);
                }
            }
        }
}

// ---------------- fused MLP: 32x32x16 split-bf16, 64x64 wave tiles ----------------
// grid 2560 (XCD-swizzled); 256 threads = 4 waves (mt=2, ct=2, 12 MFMAs/k-step).
// LDS 75.6 KB -> 2 WG/CU. B-operand: 4-slot asm register pipeline, counted
// vmcnt(4), NEVER drained mid-stream (raw lgkm-only barriers let B loads fly
// across layer boundaries). Biases staged to LDS once -> zero vm ops in-loop.
// [R13 champion structure: 407.8 us kernel, MfmaUtil 63%]
__global__ __launch_bounds__(256, 2)
void mlp_mfma(const ushort_t* __restrict__ wsU,
              const float* __restrict__ b0g, const float* __restrict__ bhg,
              const float* __restrict__ bfg, float* __restrict__ Pws) {
    __shared__ __align__(16) ushort_t smem[2 * RT * RS];  // 67,584 B, aliased:
    ushort_t* actH = smem;                                //   [64][RS] hi plane
    ushort_t* actL = smem + RT * RS;                      //   [64][RS] lo plane
    float*    yst  = (float*)smem;                        //   [64][YS] final-y staging
    __shared__ float biasLds[NHID * NU + 224];            // 8,064 B: bh[7][256], bf[224]

    const int tid  = threadIdx.x;
    const int lane = tid & 63;
    const int cg   = tid >> 6;        // wave 0..3
    const int l31  = lane & 31;
    const int lh   = lane >> 5;       // 0..1
    const int ctg0 = cg * 2;

    // XCD-aware bijective swizzle: 2560 WGs, 8 XCDs, 320/XCD
    const int bid  = blockIdx.x;
    const int work = (bid & 7) * 320 + (bid >> 3);
    const int e    = work >> 8;       // ensemble 0..9
    const int rb   = work & 255;      // 64-row block 0..255
    const int rowWG = rb * RT;

    const size_t lo8 = (size_t)lane * 8;
    const ushort_t* arH0 = actH + l31 * RS;
    const ushort_t* arL0 = actL + l31 * RS;
    const ushort_t* arH1 = actH + (32 + l31) * RS;
    const ushort_t* arL1 = actL + (32 + l31) * RS;
    const int rowb = lh * 4;          // epilogue row base within 32-tile
    const int colA = ctg0 * 32 + l31, colB = colA + 32;

    // final-layer clamped ct indices (ctg>6 duplicates 6; masked at epilogue)
    const int c0f = (ctg0 > 6) ? 6 : ctg0;
    const int c1f = (ctg0 + 1 > 6) ? 6 : ctg0 + 1;

    f32x16 acc[2][2];
    bf16x8 aH[2], aL[2];
    bf16x8 sB0h[4], sB0l[4], sB1h[4], sB1l[4];   // 4-slot B pipeline (slot = chunk&3)

    // ---- stage hidden+final biases into LDS (vm loads drained by VMWAIT0 below) ----
#pragma unroll
    for (int it = 0; it < NHID; ++it) {
        int i = it * 256 + tid;
        int L = i >> 8, c = i & 255;
        biasLds[i] = bhg[(size_t)(L * ENS + e) * NU + c];
    }
    if (tid < 224)
        biasLds[NHID * NU + tid] = (tid < OUT_DIM) ? bfg[e * OUT_DIM + tid] : 0.0f;

    // ================ layer 0 (K padded 6->16, single k-step) ================
    {
        const ushort_t* B0H = wsU + O_W0H + (size_t)e * W0_PER;
        const ushort_t* B0L = wsU + O_W0L + (size_t)e * W0_PER;
        bf16x8 b0h0 = *(const bf16x8*)(B0H + (size_t)ctg0 * 512 + lo8);
        bf16x8 b0l0 = *(const bf16x8*)(B0L + (size_t)ctg0 * 512 + lo8);
        bf16x8 b0h1 = *(const bf16x8*)(B0H + (size_t)(ctg0 + 1) * 512 + lo8);
        bf16x8 b0l1 = *(const bf16x8*)(B0L + (size_t)(ctg0 + 1) * 512 + lo8);
        bf16x8 xh[2], xl[2];
#pragma unroll
        for (int mt = 0; mt < 2; ++mt) {
            size_t xoff = ((size_t)(rb * 2 + mt) * 64 + lane) * 8;
            xh[mt] = *(const bf16x8*)(wsU + O_XH + xoff);
            xl[mt] = *(const bf16x8*)(wsU + O_XL + xoff);
        }
        float bv0 = b0g[e * NU + colA];
        float bv1 = b0g[e * NU + colB];

        f32x16 z = 0.0f;
#pragma unroll
        for (int mt = 0; mt < 2; ++mt) {
            f32x16 a0 = z, a1 = z;
            a0 = MFMA32(xh[mt], b0h0, a0);
            a1 = MFMA32(xh[mt], b0h1, a1);
            a0 = MFMA32(xl[mt], b0h0, a0);
            a1 = MFMA32(xl[mt], b0h1, a1);
            a0 = MFMA32(xh[mt], b0l0, a0);
            a1 = MFMA32(xh[mt], b0l1, a1);
            acc[mt][0] = a0; acc[mt][1] = a1;
        }

        // drain ALL compiler vm loads (x, W0, b0, bias staging), then asm-issue
        // hidden-L0 chunks 0,1 — from here on, vmcnt counts ONLY our GLOADs.
        VMWAIT0;
        {
            const ushort_t* BH0 = wsU + O_WHH + (size_t)e * WH_PER;
            const ushort_t* BL0 = wsU + O_WHL + (size_t)e * WH_PER;
#pragma unroll
            for (int cc = 0; cc < 2; ++cc) {
                size_t off = ((size_t)(cc * 8 + ctg0)) * 512 + lo8;
                GLOAD(sB0h[cc], BH0 + off);
                GLOAD(sB0l[cc], BL0 + off);
                GLOAD(sB1h[cc], BH0 + off + 512);
                GLOAD(sB1l[cc], BL0 + off + 512);
            }
        }
        store_act(actH, actL, acc, bv0, bv1, colA, colB, rowb);
        LBAR();   // lgkm-only: act + bias table visible; B loads stay in flight
    }

    // ================ 7 hidden layers (K=256, 16 k-steps, counted B stream) ================
    const ushort_t* BH = wsU + O_WHH + (size_t)e * WH_PER;
    const ushort_t* BL = wsU + O_WHL + (size_t)e * WH_PER;
#pragma unroll 1
    for (int L = 0; L < NHID; ++L) {
        // bias via LDS (lgkm, not vm — keeps the vmcnt stream exact)
        float bv0 = biasLds[L * NU + colA];
        float bv1 = biasLds[L * NU + colB];

        // next-layer chunk-0/1 addresses (runtime values, compile-time indices)
        const ushort_t *nA0[2], *nB0[2], *nA1[2], *nB1[2];
        if (L < NHID - 1) {
            const ushort_t* a_ = BH + (size_t)ENS * WH_PER;
            const ushort_t* b_ = BL + (size_t)ENS * WH_PER;
#pragma unroll
            for (int cc = 0; cc < 2; ++cc) {
                size_t off = ((size_t)(cc * 8 + ctg0)) * 512 + lo8;
                nA0[cc] = a_ + off;       nB0[cc] = b_ + off;
                nA1[cc] = a_ + off + 512; nB1[cc] = b_ + off + 512;
            }
        } else {
            const ushort_t* fh = wsU + O_WFH + (size_t)e * WF_PER;
            const ushort_t* fl = wsU + O_WFL + (size_t)e * WF_PER;
#pragma unroll
            for (int cc = 0; cc < 2; ++cc) {
                size_t o0_ = ((size_t)(cc * 7 + c0f)) * 512 + lo8;
                size_t o1_ = ((size_t)(cc * 7 + c1f)) * 512 + lo8;
                nA0[cc] = fh + o0_; nB0[cc] = fl + o0_;
                nA1[cc] = fh + o1_; nB1[cc] = fl + o1_;
            }
        }

        f32x16 z = 0.0f;
#pragma unroll
        for (int mt = 0; mt < 2; ++mt) { acc[mt][0] = z; acc[mt][1] = z; }
        aH[0] = *(const bf16x8*)(arH0 + lh * 8);
        aL[0] = *(const bf16x8*)(arL0 + lh * 8);
        aH[1] = *(const bf16x8*)(arH1 + lh * 8);
        aL[1] = *(const bf16x8*)(arL1 + lh * 8);

#pragma unroll
        for (int s = 0; s < 16; ++s) {
            // A prefetch (s+1), compiler-scheduled
            bf16x8 aHn[2], aLn[2];
            if (s < 15) {
                int kn = (s + 1) * 16 + lh * 8;
                aHn[0] = *(const bf16x8*)(arH0 + kn);
                aLn[0] = *(const bf16x8*)(arL0 + kn);
                aHn[1] = *(const bf16x8*)(arH1 + kn);
                aLn[1] = *(const bf16x8*)(arL1 + kn);
            }
            // B issue: chunk s+2 into slot (s+2)&3 (chunks >=16 are next layer's 0/1)
            {
                const ushort_t *pA0, *pB0, *pA1, *pB1;
                if (s < 14) {
                    size_t off = ((size_t)((s + 2) * 8 + ctg0)) * 512 + lo8;
                    pA0 = BH + off; pB0 = BL + off;
                    pA1 = BH + off + 512; pB1 = BL + off + 512;
                } else {
                    pA0 = nA0[s - 14]; pB0 = nB0[s - 14];
                    pA1 = nA1[s - 14]; pB1 = nB1[s - 14];
                }
                GLOAD(sB0h[(s + 2) & 3], pA0);
                GLOAD(sB0l[(s + 2) & 3], pB0);
                GLOAD(sB1h[(s + 2) & 3], pA1);
                GLOAD(sB1l[(s + 2) & 3], pB1);
            }
            VMWAIT4;                                   // chunk s+1 retired; s already ready
            __builtin_amdgcn_sched_barrier(0);         // rule 18: fence the wait
#pragma unroll
            for (int mt = 0; mt < 2; ++mt) {
                f32x16 a0 = acc[mt][0], a1 = acc[mt][1];
                a0 = MFMA32(aH[mt], sB0h[s & 3], a0);
                a1 = MFMA32(aH[mt], sB1h[s & 3], a1);
                a0 = MFMA32(aL[mt], sB0h[s & 3], a0);
                a1 = MFMA32(aL[mt], sB1h[s & 3], a1);
                a0 = MFMA32(aH[mt], sB0l[s & 3], a0);
                a1 = MFMA32(aH[mt], sB1l[s & 3], a1);
                acc[mt][0] = a0; acc[mt][1] = a1;
            }
            if (s < 15) {
                aH[0] = aHn[0]; aL[0] = aLn[0];
                aH[1] = aHn[1]; aL[1] = aLn[1];
            }
        }

        LBAR();   // all act reads of this layer done (lgkm); B loads keep flying
        store_act(actH, actL, acc, bv0, bv1, colA, colB, rowb);
        LBAR();   // act writes visible
        BH += (size_t)ENS * WH_PER;
        BL += (size_t)ENS * WH_PER;
    }

    // ================ final layer (N padded 201->224 = 7 ct-tiles) ================
    {
        const ushort_t* FH = wsU + O_WFH + (size_t)e * WF_PER;
        const ushort_t* FL = wsU + O_WFL + (size_t)e * WF_PER;
        int o0 = ctg0 * 32 + l31;
        int o1 = (ctg0 + 1) * 32 + l31;
        bool v0 = (o0 < OUT_DIM);
        bool v1 = (ctg0 + 1 < 7) && (o1 < OUT_DIM);
        float bf0 = v0 ? biasLds[NHID * NU + o0] : 0.0f;   // LDS reads (lgkm)
        float bf1 = v1 ? biasLds[NHID * NU + o1] : 0.0f;

        f32x16 z = 0.0f;
#pragma unroll
        for (int mt = 0; mt < 2; ++mt) { acc[mt][0] = z; acc[mt][1] = z; }
        aH[0] = *(const bf16x8*)(arH0 + lh * 8);
        aL[0] = *(const bf16x8*)(arL0 + lh * 8);
        aH[1] = *(const bf16x8*)(arH1 + lh * 8);
        aL[1] = *(const bf16x8*)(arL1 + lh * 8);

#pragma unroll
        for (int s = 0; s < 16; ++s) {
            bf16x8 aHn[2], aLn[2];
            if (s < 15) {
                int kn = (s + 1) * 16 + lh * 8;
                aHn[0] = *(const bf16x8*)(arH0 + kn);
                aLn[0] = *(const bf16x8*)(arL0 + kn);
                aHn[1] = *(const bf16x8*)(arH1 + kn);
                aLn[1] = *(const bf16x8*)(arL1 + kn);
            }
            if (s < 14) {
                size_t o0_ = ((size_t)((s + 2) * 7 + c0f)) * 512 + lo8;
                size_t o1_ = ((size_t)((s + 2) * 7 + c1f)) * 512 + lo8;
                GLOAD(sB0h[(s + 2) & 3], FH + o0_);
                GLOAD(sB0l[(s + 2) & 3], FL + o0_);
                GLOAD(sB1h[(s + 2) & 3], FH + o1_);
                GLOAD(sB1l[(s + 2) & 3], FL + o1_);
            }
            if (s < 15) { VMWAIT4; } else { VMWAIT0; }
            __builtin_amdgcn_sched_barrier(0);
#pragma unroll
            for (int mt = 0; mt < 2; ++mt) {
                f32x16 a0 = acc[mt][0], a1 = acc[mt][1];
                a0 = MFMA32(aH[mt], sB0h[s & 3], a0);
                a1 = MFMA32(aH[mt], sB1h[s & 3], a1);
                a0 = MFMA32(aL[mt], sB0h[s & 3], a0);
                a1 = MFMA32(aL[mt], sB1h[s & 3], a1);
                a0 = MFMA32(aH[mt], sB0l[s & 3], a0);
                a1 = MFMA32(aH[mt], sB1l[s & 3], a1);
                acc[mt][0] = a0; acc[mt][1] = a1;
            }
            if (s < 15) {
                aH[0] = aHn[0]; aL[0] = aLn[0];
                aH[1] = aHn[1]; aL[1] = aLn[1];
            }
        }

        // ---- NO atomics: stage y into LDS, reduce groups-of-10, store partials ----
        LBAR();   // all act reads done; safe to overwrite smem with yst
#pragma unroll
        for (int mt = 0; mt < 2; ++mt)
#pragma unroll
            for (int r = 0; r < 16; ++r) {
                int row = mt * 32 + rowb + (r & 3) + 8 * (r >> 2);
                if (v0) yst[row * YS + o0] = acc[mt][0][r] + bf0;
                if (v1) yst[row * YS + o1] = acc[mt][1][r] + bf1;
            }
        LBAR();

        // partial sums: P[e][rowWG+row][g] = sum over flatc in [jo*10, jo*10+10)
        const int base_jo = (e * OUT_DIM) / 10;
        const int e201 = e * OUT_DIM;
        for (int it = tid; it < RT * NG; it += 256) {
            int row = it / NG;
            int g   = it - row * NG;
            int f0  = (base_jo + g) * 10;
            float sm = 0.0f;
#pragma unroll
            for (int d = 0; d < 10; ++d) {
                int oo = f0 + d - e201;
                if (oo >= 0 && oo < OUT_DIM) sm += yst[row * YS + oo];
            }
            Pws[((size_t)e * BATCH + rowWG + row) * NG + g] = sm;
        }
    }
}

extern "C" void kernel_launch(void* const* d_in, const int* in_sizes, int n_in,
                              void* d_out, int out_size, void* d_ws, size_t ws_size,
                              hipStream_t stream) {
    const float* x  = (const float*)d_in[0];
    const float* W0 = (const float*)d_in[1];
    const float* b0 = (const float*)d_in[2];
    const float* Wh = (const float*)d_in[3];
    const float* bh = (const float*)d_in[4];
    const float* Wf = (const float*)d_in[5];
    const float* bf = (const float*)d_in[6];
    float* out = (float*)d_out;
    ushort_t* ws = (ushort_t*)d_ws;            // needs ~36 MB
    float* Pws = (float*)(ws + O_P);           // P[ENS][BATCH][NG]

    prep_all<<<(PREP_TOT + 255) / 256, 256, 0, stream>>>(Wh, W0, Wf, x, ws);
    mlp_mfma<<<dim3(BATCH / RT * ENS), 256, 0, stream>>>(ws, b0, bh, bf, Pws);
    reduce_mean<<<(BATCH * OUT_DIM + 255) / 256, 256, 0, stream>>>(Pws, out);
}